// Round 15
// baseline (84.246 us; speedup 1.0000x reference)
//
#include <hip/hip_runtime.h>
#include <hip/hip_bf16.h>
#include <cstdint>

#define N_DIM 4096
#define K_DIM 2048           // i8 elements per row
#define NKT 32               // 32 K-tiles of 64
#define QSCALE 24.0f
#define QINV (1.0f / 24.0f)

typedef float floatx4 __attribute__((ext_vector_type(4)));
typedef int intx4 __attribute__((ext_vector_type(4)));
typedef unsigned short ushort8 __attribute__((ext_vector_type(8)));
typedef unsigned long long ull;

__device__ __forceinline__ unsigned short f2bf(float f) {
    unsigned int u = __builtin_bit_cast(unsigned int, f);
    unsigned int r = (u + 0x7fffu + ((u >> 16) & 1u)) >> 16;  // RNE
    return (unsigned short)r;
}

__device__ __forceinline__ float bf2f(unsigned short b) {
    return __uint_as_float(((unsigned)b) << 16);
}

__device__ __forceinline__ void gld_lds16(const void* g, void* l) {
    __builtin_amdgcn_global_load_lds(
        (const __attribute__((address_space(1))) unsigned int*)g,
        (__attribute__((address_space(3))) unsigned int*)l,
        16, 0, 0);
}

// ---- Kernel 0: quantize fp32 -> int8 (scale 24) into k-major panels --------
// Qt layout: byte(kslot, row) = (kslot*4096 + row)*16, kslot = k/16 (0..127).
__global__ __launch_bounds__(256)
void prep_kernel(const float* __restrict__ X, char* __restrict__ Qt,
                 int* __restrict__ sqi) {
    const int row = blockIdx.x;
    const int tid = threadIdx.x;
    const float* xr = X + (size_t)row * K_DIM;
    floatx4 a = *(const floatx4*)(xr + tid * 8);
    floatx4 b = *(const floatx4*)(xr + tid * 8 + 4);
    int s = 0;
    unsigned lo = 0, hi = 0;
#pragma unroll
    for (int e = 0; e < 4; ++e) {
        int v = __float2int_rn(a[e] * QSCALE);
        v = min(127, max(-127, v));
        s += v * v;
        lo |= ((unsigned)(v & 0xff)) << (8 * e);
        int w = __float2int_rn(b[e] * QSCALE);
        w = min(127, max(-127, w));
        s += w * w;
        hi |= ((unsigned)(w & 0xff)) << (8 * e);
    }
    *(int2*)(Qt + ((size_t)(tid >> 1) * 4096 + row) * 16 + (tid & 1) * 8) =
        make_int2((int)lo, (int)hi);
#pragma unroll
    for (int off = 32; off; off >>= 1) s += __shfl_down(s, off);
    __shared__ int wsum[4];
    const int wave = tid >> 6, lane = tid & 63;
    if (lane == 0) wsum[wave] = s;
    __syncthreads();
    if (tid == 0) sqi[row] = wsum[0] + wsum[1] + wsum[2] + wsum[3];
}

// ---- Kernel 1: 256x128 i8 GEMM, wave tile 64x128 (NO A duplication) --------
// 256 thr = 4 waves; wave w owns rows w*64..+64 EXCLUSIVELY -> A loaded once
// (global->reg, dbuf afX/afY); B (4-way reuse) via tri-buffered LDS 24KB.
// Per-CU-step traffic: A 32KB + B 16KB L2 (~1260cyc) | LDS 768 | MFMA 1306 —
// all terms <= MFMA (R13 was LDS-heavy, R14 was L2-heavy: dominant term
// always == measured; this config makes MFMA the dominant term).
// acc = 8n x 4m intx4 = 128 AGPR; launch_bounds(256,2) caps 256 regs/wave.
// Tile body t: [LOAD_A(t+1) x4 | vmcnt(6) | BAR | STG_B(t+2) x2 |
//               8x ds_read B(t) | 32 MFMA]
// vmcnt(6) leaves {B(t+1)2, A(t+1)4}, retires {A(t), B(t)} (FIFO, in-order
// retire); BAR makes all waves' B(t) visible before its ds_reads. WAR on
// B-buf[(t+2)%3]: readers of B(t-1) finished before BAR(t). Tail: vmcnt(0).
// EPILOGUE also emits per-(block,row) hardest-pos/neg partials (packed
// (bf16bits<<32|idx) monoid, bitwise-identical to stats_loss's old phase 1):
// in-reg n-reduce -> LDS scatter sMax/sMin[row][fr] (one owner per slot,
// no shuffles) -> 16-entry reduce -> Gmax/Gmin[row][bj] (2MB).
#define BAR() { __builtin_amdgcn_s_barrier(); asm volatile("" ::: "memory"); }
#define PRIO1() __builtin_amdgcn_s_setprio(1)
#define PRIO0() __builtin_amdgcn_s_setprio(0)
#define VMCNT6() { asm volatile("s_waitcnt vmcnt(6)" ::: "memory"); \
                   __builtin_amdgcn_sched_barrier(0); }
#define VMCNT0() { asm volatile("s_waitcnt vmcnt(0)" ::: "memory"); \
                   __builtin_amdgcn_sched_barrier(0); }
#define KTB 262144   // one K-tile advance in Qt = 4 kslots * 4096 rows * 16B
#define LOAD_A(DST) { \
    asm volatile("global_load_dwordx4 %0, %1, off"            : "=&v"(DST[0]) : "v"(aAddr)); \
    asm volatile("global_load_dwordx4 %0, %1, off offset:256" : "=&v"(DST[1]) : "v"(aAddr)); \
    asm volatile("global_load_dwordx4 %0, %1, off offset:512" : "=&v"(DST[2]) : "v"(aAddr)); \
    asm volatile("global_load_dwordx4 %0, %1, off offset:768" : "=&v"(DST[3]) : "v"(aAddr)); \
    aAddr += KTB; }
#define STG_B(KT, BB) { \
    gld_lds16(bSrc + (size_t)(KT) * KTB,          lds + (BB) + widB); \
    gld_lds16(bSrc + (size_t)(KT) * KTB + 131072, lds + (BB) + 4096 + widB); }
#define MM32(AF) { _Pragma("unroll") for (int n_ = 0; n_ < 8; ++n_) { \
    _Pragma("unroll") for (int m_ = 0; m_ < 4; ++m_) { \
        acc[n_][m_] = __builtin_amdgcn_mfma_i32_16x16x64_i8( \
            AF[m_], bfv[n_], acc[n_][m_], 0, 0, 0); } } }
#define TILE_BODY(T, LD, USE) { \
    if ((T) < NKT - 1) LOAD_A(LD); \
    if ((T) < NKT - 1) { VMCNT6(); } else { VMCNT0(); } \
    BAR(); \
    if ((T) < NKT - 2) STG_B((T) + 2, sb); \
    _Pragma("unroll") \
    for (int n_ = 0; n_ < 8; ++n_) bfv[n_] = *(const intx4*)(lds + cb + rB[n_]); \
    PRIO1(); MM32(USE); PRIO0(); \
    cb += 8192; if (cb >= 24576) cb = 0; \
    sb += 8192; if (sb >= 24576) sb = 0; }

__global__ __launch_bounds__(256, 2)
void gemm_dist(const char* __restrict__ Qt, const int* __restrict__ sqi,
               const int* __restrict__ tgt, unsigned short* __restrict__ Db,
               ull* __restrict__ Gmax, ull* __restrict__ Gmin) {
    __shared__ char lds[65536];   // loop: first 24KB (3x8KB B); epi: 64KB
    const int tid = threadIdx.x;
    const int wid = tid >> 6, lane = tid & 63;
    const int fr = lane & 15, ksub = lane >> 4;
    const int widB = wid * 1024;

    int rB[8];
#pragma unroll
    for (int n = 0; n < 8; ++n) rB[n] = (ksub * 128 + n * 16 + fr) * 16;

    // XCD-chunked: 64 blocks/XCD as (bi 0..15) x (bj 0..31), bijective
    const int xcd = blockIdx.x & 7, kk = blockIdx.x >> 3;
    const int bi = (kk >> 3) | ((xcd & 1) << 3);
    const int bj = (kk & 7) | ((xcd >> 1) << 3);
    const int rowC0 = bi * 256, colC0 = bj * 128;

    // A source: lane-private, wave-exclusive rows (no duplication)
    unsigned long long aAddr = (unsigned long long)(Qt +
        ((size_t)ksub * 4096 + rowC0 + wid * 64 + fr) * 16);
    // B stage source: pos16 = tid -> kslot = tid>>7, col = tid&127 (coalesced)
    const char* bSrc = Qt + ((size_t)(tid >> 7) * 4096 + colC0 + (tid & 127)) * 16;

    intx4 acc[8][4];
#pragma unroll
    for (int a1 = 0; a1 < 8; ++a1)
#pragma unroll
    for (int a2 = 0; a2 < 4; ++a2) acc[a1][a2] = (intx4){0, 0, 0, 0};
    intx4 afX[4], afY[4], bfv[8];

    // prologue: A(0)->afX, stage B(0)->buf0, B(1)->buf1
    LOAD_A(afX);
    STG_B(0, 0);
    STG_B(1, 8192);

    int cb = 0, sb = 16384;
#pragma unroll 1
    for (int it = 0; it < NKT / 2; ++it) {
        const int t0 = it * 2;
        TILE_BODY(t0,     afY, afX);
        TILE_BODY(t0 + 1, afX, afY);
    }

    // ---- epilogue: D write + per-(block,row) packed min/max partials -------
    BAR();   // all waves done reading B(31) before LDS reuse
    ull* sMax = (ull*)lds;              // [256 rows][16 fr]
    ull* sMin = (ull*)(lds + 32768);    // [256 rows][16 fr]
    int tc[8];
#pragma unroll
    for (int n = 0; n < 8; ++n) tc[n] = tgt[colC0 + n * 16 + fr];
#pragma unroll
    for (int m = 0; m < 4; ++m) {
#pragma unroll
        for (int r = 0; r < 4; ++r) {
            const int rowL = wid * 64 + m * 16 + ksub * 4 + r;
            const int row = rowC0 + rowL;
            const int sqr = sqi[row];
            const int tr = tgt[row];
            ull kmx = 0ULL, kmn = ~0ULL;
#pragma unroll
            for (int n = 0; n < 8; ++n) {
                const int col = colC0 + n * 16 + fr;
                const int v = sqr + sqi[col] - 2 * acc[n][m][r];
                const float d = (v > 0) ? sqrtf((float)v) * QINV : 1e-6f;
                const unsigned short db16 = f2bf(d);
                Db[(size_t)row * N_DIM + col] = db16;
                const ull db = (ull)db16 << 32;
                if (tc[n] == tr) { ull k = db | (unsigned)col;  if (k > kmx) kmx = k; }
                else             { ull k = db | (unsigned)~col; if (k < kmn) kmn = k; }
            }
            sMax[rowL * 16 + fr] = kmx;
            sMin[rowL * 16 + fr] = kmn;
        }
    }
    BAR();
    {   // thread tid reduces row tid's 16 fr-entries
        const ull* rm = sMax + tid * 16;
        const ull* rn = sMin + tid * 16;
        ull km = rm[0], kn = rn[0];
#pragma unroll
        for (int e = 1; e < 16; ++e) {
            if (rm[e] > km) km = rm[e];
            if (rn[e] < kn) kn = rn[e];
        }
        Gmax[(size_t)(rowC0 + tid) * 32 + bj] = km;
        Gmin[(size_t)(rowC0 + tid) * 32 + bj] = kn;
    }
}

// ---- Kernel 2: stats from partials + third-class scan + loss ---------------
__global__ __launch_bounds__(256)
void stats_loss(const unsigned short* __restrict__ Db, const int* __restrict__ tgt,
                const ull* __restrict__ Gmax, const ull* __restrict__ Gmin,
                float* __restrict__ lossArr) {
    const int i = blockIdx.x, tid = threadIdx.x;
    const int ti = tgt[i];
    __shared__ ull sM[32], sN2[32];
    if (tid < 32) sM[tid] = Gmax[(size_t)i * 32 + tid];
    else if (tid < 64) sN2[tid - 32] = Gmin[(size_t)i * 32 + (tid - 32)];
    __syncthreads();
    for (int off = 16; off; off >>= 1) {
        if (tid < off) { if (sM[tid + off] > sM[tid]) sM[tid] = sM[tid + off]; }
        else if (tid >= 32 && tid < 32 + off) {
            if (sN2[tid - 32 + off] < sN2[tid - 32]) sN2[tid - 32] = sN2[tid - 32 + off];
        }
        __syncthreads();
    }
    const ull km = sM[0], kn = sN2[0];
    const float ap = bf2f((unsigned short)(km >> 32));
    const int p = (int)(unsigned)(km & 0xFFFFFFFFu);
    const float an = bf2f((unsigned short)(kn >> 32));
    const int q = (int)~(unsigned)(kn & 0xFFFFFFFFu);

    // phase 2: third-class min over row q
    const int lq = tgt[q];
    const unsigned short* rowq = Db + (size_t)q * N_DIM;
    ull kr = ~0ULL;
#pragma unroll
    for (int it = 0; it < 2; ++it) {
        const int j0 = (it * 256 + tid) * 8;
        ushort8 d = *(const ushort8*)(rowq + j0);
        intx4 ta = *(const intx4*)(tgt + j0);
        intx4 tb = *(const intx4*)(tgt + j0 + 4);
#pragma unroll
        for (int e = 0; e < 8; ++e) {
            const int j = j0 + e;
            const int tl = (e < 4) ? ta[e] : tb[e - 4];
            if (tl != ti && tl != lq) {
                ull k = ((ull)d[e] << 32) | (unsigned)~j;
                if (k < kr) kr = k;
            }
        }
    }
    __shared__ ull sR[256];
    sR[tid] = kr;
    __syncthreads();
    for (int off = 128; off; off >>= 1) {
        if (tid < off) { if (sR[tid + off] < sR[tid]) sR[tid] = sR[tid + off]; }
        __syncthreads();
    }
    if (tid == 0) {
        const ull kk = sR[0];
        const float okmin = bf2f((unsigned short)(kk >> 32));
        const int r = (int)~(unsigned)(kk & 0xFFFFFFFFu);
        const float an2 = bf2f(Db[(size_t)p * N_DIM + q]);
        const float an3 = bf2f(Db[(size_t)i * N_DIM + r]);
        lossArr[i] = fmaxf(ap - an, 0.f) + fabsf(an - an2) + fabsf(an3 - okmin);
    }
}

// ---- Kernel 3: final sum / n ------------------------------------------------
__global__ __launch_bounds__(256)
void finred(const float* __restrict__ lossArr, float* __restrict__ out) {
    const int tid = threadIdx.x;
    float s = 0.f;
    for (int j = tid; j < N_DIM; j += 256) s += lossArr[j];
#pragma unroll
    for (int off = 32; off; off >>= 1) s += __shfl_down(s, off);
    __shared__ float w[4];
    const int wave = tid >> 6, lane = tid & 63;
    if (lane == 0) w[wave] = s;
    __syncthreads();
    if (tid == 0) out[0] = (w[0] + w[1] + w[2] + w[3]) * (1.0f / (float)N_DIM);
}

extern "C" void kernel_launch(void* const* d_in, const int* in_sizes, int n_in,
                              void* d_out, int out_size, void* d_ws, size_t ws_size,
                              hipStream_t stream) {
    const float* X = (const float*)d_in[0];
    const int* tgt = (const int*)d_in[1];
    float* out = (float*)d_out;

    char* w = (char*)d_ws;
    char* Qt = w;                                             // 8 MB (k-major)
    unsigned short* Db = (unsigned short*)(w + ((size_t)16 << 20));  // 32 MB bf16
    int* sqi = (int*)(w + ((size_t)80 << 20));                // 16 KB
    float* lossArr = (float*)(sqi + N_DIM);                   // 16 KB
    ull* Gmax = (ull*)(w + ((size_t)82 << 20));               // 1 MB
    ull* Gmin = Gmax + (size_t)N_DIM * 32;                    // 1 MB

    prep_kernel<<<N_DIM, 256, 0, stream>>>(X, Qt, sqi);
    gemm_dist<<<512, 256, 0, stream>>>(Qt, sqi, tgt, Db, Gmax, Gmin);
    stats_loss<<<N_DIM, 256, 0, stream>>>(Db, tgt, Gmax, Gmin, lossArr);
    finred<<<1, 256, 0, stream>>>(lossArr, out);
}

// Round 16
// 76.813 us; speedup vs baseline: 1.0968x; 1.0968x over previous
//
#include <hip/hip_runtime.h>
#include <hip/hip_bf16.h>
#include <cstdint>

#define N_DIM 4096
#define K_DIM 2048           // i8 elements per row
#define NKT 32               // 32 K-tiles of 64
#define QSCALE 24.0f
#define QINV (1.0f / 24.0f)

typedef float floatx4 __attribute__((ext_vector_type(4)));
typedef int intx4 __attribute__((ext_vector_type(4)));
typedef unsigned short ushort8 __attribute__((ext_vector_type(8)));
typedef unsigned long long ull;

__device__ __forceinline__ unsigned short f2bf(float f) {
    unsigned int u = __builtin_bit_cast(unsigned int, f);
    unsigned int r = (u + 0x7fffu + ((u >> 16) & 1u)) >> 16;  // RNE
    return (unsigned short)r;
}

__device__ __forceinline__ float bf2f(unsigned short b) {
    return __uint_as_float(((unsigned)b) << 16);
}

__device__ __forceinline__ void gld_lds16(const void* g, void* l) {
    __builtin_amdgcn_global_load_lds(
        (const __attribute__((address_space(1))) unsigned int*)g,
        (__attribute__((address_space(3))) unsigned int*)l,
        16, 0, 0);
}

// ---- Kernel 0: quantize fp32 -> int8 (scale 24) into k-major panels --------
// Qt layout: byte(kslot, row) = (kslot*4096 + row)*16, kslot = k/16 (0..127).
__global__ __launch_bounds__(256)
void prep_kernel(const float* __restrict__ X, char* __restrict__ Qt,
                 int* __restrict__ sqi) {
    const int row = blockIdx.x;
    const int tid = threadIdx.x;
    const float* xr = X + (size_t)row * K_DIM;
    floatx4 a = *(const floatx4*)(xr + tid * 8);
    floatx4 b = *(const floatx4*)(xr + tid * 8 + 4);
    int s = 0;
    unsigned lo = 0, hi = 0;
#pragma unroll
    for (int e = 0; e < 4; ++e) {
        int v = __float2int_rn(a[e] * QSCALE);
        v = min(127, max(-127, v));
        s += v * v;
        lo |= ((unsigned)(v & 0xff)) << (8 * e);
        int w = __float2int_rn(b[e] * QSCALE);
        w = min(127, max(-127, w));
        s += w * w;
        hi |= ((unsigned)(w & 0xff)) << (8 * e);
    }
    *(int2*)(Qt + ((size_t)(tid >> 1) * 4096 + row) * 16 + (tid & 1) * 8) =
        make_int2((int)lo, (int)hi);
#pragma unroll
    for (int off = 32; off; off >>= 1) s += __shfl_down(s, off);
    __shared__ int wsum[4];
    const int wave = tid >> 6, lane = tid & 63;
    if (lane == 0) wsum[wave] = s;
    __syncthreads();
    if (tid == 0) sqi[row] = wsum[0] + wsum[1] + wsum[2] + wsum[3];
}

// ---- Kernel 1: 256x256 int8 MFMA GEMM + bf16 distance epilogue -------------
// R11 kernel verbatim (best measured total config: gemm 45.6 us, VGPR 108,
// 0 bank conflicts, FETCH 33 MB, absmax 0.0625). 512 thr = 8 waves (2Mx4N),
// mfma_i32_16x16x64_i8, tri-buffered 96KB LDS, 2 phases/K-tile:
//   ph1: RD Alo(4)+B(4) | STG B0,B1(t+2) | BAR | 16 MFMA (MH=0)
//   ph2: RD Ahi(4)      | STG A0,A1(t+2) | vmcnt(4) | BAR | 16 MFMA (MH=1)
// Staging sources read k-major Qt panels -> consecutive lanes read
// consecutive 16B (coalesced). LDS region (8KB): pos16 = kslot*128 + row.
// D stored bf16 (halves write + downstream read traffic).
#define BAR() __builtin_amdgcn_s_barrier()
#define PRIO1() __builtin_amdgcn_s_setprio(1)
#define PRIO0() __builtin_amdgcn_s_setprio(0)
#define VMCNT4() asm volatile("s_waitcnt vmcnt(4)" ::: "memory")
#define VMCNT0() asm volatile("s_waitcnt vmcnt(0)" ::: "memory")
#define MM8(MHI, AF) { _Pragma("unroll") for (int n_ = 0; n_ < 4; ++n_) { \
    _Pragma("unroll") for (int m_ = 0; m_ < 4; ++m_) { \
        acc[MHI][n_][m_] = __builtin_amdgcn_mfma_i32_16x16x64_i8( \
            AF[m_], bfv[n_], acc[MHI][n_][m_], 0, 0, 0); } } }
#define KTB 262144   // one K-tile advance in Qt = 4 kslots * 4096 rows * 16B
#define STG_B(KT, BB) { \
    gld_lds16(bSt + (size_t)(KT) * KTB,        lds + (BB) + 16384 + widB); \
    gld_lds16(bSt + (size_t)(KT) * KTB + 2048, lds + (BB) + 24576 + widB); }
#define STG_A(KT, BB) { \
    gld_lds16(aSt + (size_t)(KT) * KTB,        lds + (BB) + widB); \
    gld_lds16(aSt + (size_t)(KT) * KTB + 2048, lds + (BB) + 8192 + widB); }

__global__ __launch_bounds__(512, 2)
void gemm_dist(const char* __restrict__ Qt, const int* __restrict__ sqi,
               unsigned short* __restrict__ Db) {
    __shared__ char lds[98304];   // 96 KB = 3 bufs x (A0,A1,B0,B1 of 8KB)
    const int tid = threadIdx.x;
    const int wid = tid >> 6, lane = tid & 63;
    const int wr = wid >> 2, wc = wid & 3;
    const int fr = lane & 15, ksub = lane >> 4;
    const int widB = wid * 1024;

    int rA[4], rB[4];
#pragma unroll
    for (int m = 0; m < 4; ++m) rA[m] = (ksub * 128 + m * 16 + fr) * 16;
#pragma unroll
    for (int n = 0; n < 4; ++n) rB[n] = (ksub * 128 + (wc & 1) * 64 + n * 16 + fr) * 16;
    const int aRegOff = wr * 8192;
    const int bRegOff = 16384 + (wc >> 1) * 8192;

    const int swz = (blockIdx.x & 7) * 32 + (blockIdx.x >> 3);  // XCD-chunked
    const int bi = swz >> 4, bj = swz & 15;
    const int rowC0 = bi * 256, colC0 = bj * 256;

    const int srow = tid & 127;
    const int sks = tid >> 7;
    const char* aSt = Qt + ((size_t)sks * 4096 + rowC0 + srow) * 16;
    const char* bSt = Qt + ((size_t)sks * 4096 + colC0 + srow) * 16;

    intx4 acc[2][4][4];
#pragma unroll
    for (int a0 = 0; a0 < 2; ++a0)
#pragma unroll
    for (int a1 = 0; a1 < 4; ++a1)
#pragma unroll
    for (int a2 = 0; a2 < 4; ++a2) acc[a0][a1][a2] = (intx4){0, 0, 0, 0};
    intx4 aflo[4], afhi[4], bfv[4];

    // prologue: t0 (4 loads) then t1 (4); vmcnt(4) = t0 landed
    STG_B(0, 0); STG_A(0, 0);
    STG_B(1, 32768); STG_A(1, 32768);
    VMCNT4();
    BAR();

    int cb = 0, sb = 65536;   // current / staging(t+2) buffer byte base
    for (int t = 0; t < NKT; ++t) {
        const bool pf = (t < NKT - 2);
        const char* bufA = lds + cb + aRegOff;
        const char* bufBp = lds + cb + bRegOff;
        // ph1: RD Alo + B | STG (t+2).B0,B1 | BAR | MFMA MH=0
#pragma unroll
        for (int m = 0; m < 4; ++m) aflo[m] = *(const intx4*)(bufA + rA[m]);
#pragma unroll
        for (int n = 0; n < 4; ++n) bfv[n] = *(const intx4*)(bufBp + rB[n]);
        if (pf) STG_B(t + 2, sb);
        BAR(); PRIO1(); MM8(0, aflo); PRIO0();
        // ph2: RD Ahi | STG (t+2).A0,A1 | vmcnt | BAR | MFMA MH=1
#pragma unroll
        for (int m = 0; m < 4; ++m) afhi[m] = *(const intx4*)(bufA + 1024 + rA[m]);
        if (pf) { STG_A(t + 2, sb); VMCNT4(); } else { VMCNT0(); }
        BAR(); PRIO1(); MM8(1, afhi); PRIO0();
        cb += 32768; if (cb >= 98304) cb = 0;
        sb += 32768; if (sb >= 98304) sb = 0;
    }

    // epilogue: D[i][j] = bf16( (v>0) ? sqrt(v)/24 : 1e-6 ), v exact int32
#pragma unroll
    for (int MH = 0; MH < 2; ++MH)
#pragma unroll
    for (int n = 0; n < 4; ++n) {
        const int col = colC0 + wc * 64 + n * 16 + fr;
        const int sqc = sqi[col];
#pragma unroll
        for (int m = 0; m < 4; ++m) {
            const int row0 = rowC0 + wr * 128 + MH * 64 + m * 16 + ksub * 4;
#pragma unroll
            for (int r = 0; r < 4; ++r) {
                const int v = sqi[row0 + r] + sqc - 2 * acc[MH][n][m][r];
                const float d = (v > 0) ? sqrtf((float)v) * QINV : 1e-6f;
                Db[(size_t)(row0 + r) * N_DIM + col] = f2bf(d);
            }
        }
    }
}

// ---- Kernel 2: fused row stats + third-class scan + loss (bf16 D) ----------
// NEW vs R11: wave-level __shfl_xor butterfly reductions (6 steps, 64 lanes)
// + single 8-word LDS combine replace the 256-entry LDS trees (~16 barriers
// -> 2). Max/min monoids are order-independent -> packed-key selections
// bitwise-identical to R11.
__global__ __launch_bounds__(256)
void stats_loss(const unsigned short* __restrict__ Db, const int* __restrict__ tgt,
                float* __restrict__ lossArr) {
    const int i = blockIdx.x, tid = threadIdx.x;
    const int lane = tid & 63, wave = tid >> 6;
    const int ti = tgt[i];
    const unsigned short* row = Db + (size_t)i * N_DIM;
    ull kmax = 0ULL, kmin = ~0ULL;
#pragma unroll
    for (int it = 0; it < 2; ++it) {
        const int j0 = (it * 256 + tid) * 8;
        ushort8 d = *(const ushort8*)(row + j0);
        intx4 ta = *(const intx4*)(tgt + j0);
        intx4 tb = *(const intx4*)(tgt + j0 + 4);
#pragma unroll
        for (int e = 0; e < 8; ++e) {
            const int j = j0 + e;
            const int tl = (e < 4) ? ta[e] : tb[e - 4];
            const ull db = (ull)d[e] << 32;
            if (tl == ti) { ull k = db | (unsigned)j;  if (k > kmax) kmax = k; }
            else          { ull k = db | (unsigned)~j; if (k < kmin) kmin = k; }
        }
    }
#pragma unroll
    for (int off = 32; off; off >>= 1) {
        ull o = __shfl_xor(kmax, off); if (o > kmax) kmax = o;
        o = __shfl_xor(kmin, off);     if (o < kmin) kmin = o;
    }
    __shared__ ull sW[8];
    if (lane == 0) { sW[wave] = kmax; sW[4 + wave] = kmin; }
    __syncthreads();
    ull km = sW[0], kn = sW[4];
#pragma unroll
    for (int w2 = 1; w2 < 4; ++w2) {
        if (sW[w2] > km) km = sW[w2];
        if (sW[4 + w2] < kn) kn = sW[4 + w2];
    }
    const float ap = bf2f((unsigned short)(km >> 32));
    const int p = (int)(unsigned)(km & 0xFFFFFFFFu);
    const float an = bf2f((unsigned short)(kn >> 32));
    const int q = (int)~(unsigned)(kn & 0xFFFFFFFFu);

    // phase 2: third-class min over row q (labels != ti and != tgt[q])
    const int lq = tgt[q];
    const unsigned short* rowq = Db + (size_t)q * N_DIM;
    ull kr = ~0ULL;
#pragma unroll
    for (int it = 0; it < 2; ++it) {
        const int j0 = (it * 256 + tid) * 8;
        ushort8 d = *(const ushort8*)(rowq + j0);
        intx4 ta = *(const intx4*)(tgt + j0);
        intx4 tb = *(const intx4*)(tgt + j0 + 4);
#pragma unroll
        for (int e = 0; e < 8; ++e) {
            const int j = j0 + e;
            const int tl = (e < 4) ? ta[e] : tb[e - 4];
            if (tl != ti && tl != lq) {
                ull k = ((ull)d[e] << 32) | (unsigned)~j;
                if (k < kr) kr = k;
            }
        }
    }
#pragma unroll
    for (int off = 32; off; off >>= 1) {
        ull o = __shfl_xor(kr, off); if (o < kr) kr = o;
    }
    __shared__ ull sR[4];
    if (lane == 0) sR[wave] = kr;
    __syncthreads();
    if (tid == 0) {
        ull kk = sR[0];
#pragma unroll
        for (int w2 = 1; w2 < 4; ++w2) if (sR[w2] < kk) kk = sR[w2];
        const float okmin = bf2f((unsigned short)(kk >> 32));
        const int r = (int)~(unsigned)(kk & 0xFFFFFFFFu);
        const float an2 = bf2f(Db[(size_t)p * N_DIM + q]);
        const float an3 = bf2f(Db[(size_t)i * N_DIM + r]);
        lossArr[i] = fmaxf(ap - an, 0.f) + fabsf(an - an2) + fabsf(an3 - okmin);
    }
}

// ---- Kernel 3: final sum / n ------------------------------------------------
__global__ __launch_bounds__(256)
void finred(const float* __restrict__ lossArr, float* __restrict__ out) {
    const int tid = threadIdx.x;
    float s = 0.f;
    for (int j = tid; j < N_DIM; j += 256) s += lossArr[j];
#pragma unroll
    for (int off = 32; off; off >>= 1) s += __shfl_down(s, off);
    __shared__ float w[4];
    const int wave = tid >> 6, lane = tid & 63;
    if (lane == 0) w[wave] = s;
    __syncthreads();
    if (tid == 0) out[0] = (w[0] + w[1] + w[2] + w[3]) * (1.0f / (float)N_DIM);
}

extern "C" void kernel_launch(void* const* d_in, const int* in_sizes, int n_in,
                              void* d_out, int out_size, void* d_ws, size_t ws_size,
                              hipStream_t stream) {
    const float* X = (const float*)d_in[0];
    const int* tgt = (const int*)d_in[1];
    float* out = (float*)d_out;

    char* w = (char*)d_ws;
    char* Qt = w;                                             // 8 MB (k-major)
    unsigned short* Db = (unsigned short*)(w + ((size_t)16 << 20));  // 32 MB bf16
    int* sqi = (int*)(w + ((size_t)80 << 20));                // 16 KB
    float* lossArr = (float*)(sqi + N_DIM);                   // 16 KB

    prep_kernel<<<N_DIM, 256, 0, stream>>>(X, Qt, sqi);
    gemm_dist<<<256, 512, 0, stream>>>(Qt, sqi, Db);
    stats_loss<<<N_DIM, 256, 0, stream>>>(Db, tgt, lossArr);
    finred<<<1, 256, 0, stream>>>(lossArr, out);
}

// Round 17
// 76.400 us; speedup vs baseline: 1.1027x; 1.0054x over previous
//
#include <hip/hip_runtime.h>
#include <hip/hip_bf16.h>
#include <cstdint>

#define N_DIM 4096
#define K_DIM 2048           // i8 elements per row
#define NKT 32               // 32 K-tiles of 64
#define QSCALE 24.0f
#define QINV (1.0f / 24.0f)

typedef float floatx4 __attribute__((ext_vector_type(4)));
typedef int intx4 __attribute__((ext_vector_type(4)));
typedef unsigned short ushort8 __attribute__((ext_vector_type(8)));
typedef unsigned long long ull;

__device__ __forceinline__ unsigned short f2bf(float f) {
    unsigned int u = __builtin_bit_cast(unsigned int, f);
    unsigned int r = (u + 0x7fffu + ((u >> 16) & 1u)) >> 16;  // RNE
    return (unsigned short)r;
}

__device__ __forceinline__ float bf2f(unsigned short b) {
    return __uint_as_float(((unsigned)b) << 16);
}

__device__ __forceinline__ void gld_lds16(const void* g, void* l) {
    __builtin_amdgcn_global_load_lds(
        (const __attribute__((address_space(1))) unsigned int*)g,
        (__attribute__((address_space(3))) unsigned int*)l,
        16, 0, 0);
}

// ---- Kernel 0: quantize fp32 -> int8 (scale 24) into k-major panels --------
// Qt layout: byte(kslot, row) = (kslot*4096 + row)*16, kslot = k/16 (0..127).
__global__ __launch_bounds__(256)
void prep_kernel(const float* __restrict__ X, char* __restrict__ Qt,
                 int* __restrict__ sqi) {
    const int row = blockIdx.x;
    const int tid = threadIdx.x;
    const float* xr = X + (size_t)row * K_DIM;
    floatx4 a = *(const floatx4*)(xr + tid * 8);
    floatx4 b = *(const floatx4*)(xr + tid * 8 + 4);
    int s = 0;
    unsigned lo = 0, hi = 0;
#pragma unroll
    for (int e = 0; e < 4; ++e) {
        int v = __float2int_rn(a[e] * QSCALE);
        v = min(127, max(-127, v));
        s += v * v;
        lo |= ((unsigned)(v & 0xff)) << (8 * e);
        int w = __float2int_rn(b[e] * QSCALE);
        w = min(127, max(-127, w));
        s += w * w;
        hi |= ((unsigned)(w & 0xff)) << (8 * e);
    }
    *(int2*)(Qt + ((size_t)(tid >> 1) * 4096 + row) * 16 + (tid & 1) * 8) =
        make_int2((int)lo, (int)hi);
#pragma unroll
    for (int off = 32; off; off >>= 1) s += __shfl_down(s, off);
    __shared__ int wsum[4];
    const int wave = tid >> 6, lane = tid & 63;
    if (lane == 0) wsum[wave] = s;
    __syncthreads();
    if (tid == 0) sqi[row] = wsum[0] + wsum[1] + wsum[2] + wsum[3];
}

// ---- Kernel 1: 256x256 int8 MFMA GEMM + bf16 distance epilogue -------------
// R11 geometry (512 thr = 8 waves 2Mx4N, mfma_i32_16x16x64_i8, k-major Qt
// coalesced staging, bf16 D) with a MERGED single phase per K-tile and
// QUAD-buffered 128KB LDS:
//   tile t: [RD 12 b128 (Alo,Ahi,B) | STG all 4 halves of (t+2) |
//            vmcnt(4) | BAR | 32 MFMA]
// Sync points halve vs R11 (64 -> 32 barriers + 32 vmcnt); the post-BAR
// 32-MFMA window overlaps the next tile's LDS reads across 2 waves/SIMD.
// FIFO: end of tile t outstanding = {stage(t+1), stage(t+2)} = 8 ->
// vmcnt(4) retires stage(t+1) exactly; t=NKT-2 drains vmcnt(0).
// WAR: stage(t+2) -> buf[(t+2)%4], last read tile t-2 -> 2-barrier gap
// (same margin as R11). Arithmetic bit-identical; absmax must stay 0.0625.
#define BAR() __builtin_amdgcn_s_barrier()
#define PRIO1() __builtin_amdgcn_s_setprio(1)
#define PRIO0() __builtin_amdgcn_s_setprio(0)
#define VMCNT4() asm volatile("s_waitcnt vmcnt(4)" ::: "memory")
#define VMCNT0() asm volatile("s_waitcnt vmcnt(0)" ::: "memory")
#define MM8(MHI, AF) { _Pragma("unroll") for (int n_ = 0; n_ < 4; ++n_) { \
    _Pragma("unroll") for (int m_ = 0; m_ < 4; ++m_) { \
        acc[MHI][n_][m_] = __builtin_amdgcn_mfma_i32_16x16x64_i8( \
            AF[m_], bfv[n_], acc[MHI][n_][m_], 0, 0, 0); } } }
#define KTB 262144   // one K-tile advance in Qt = 4 kslots * 4096 rows * 16B
#define STG_ALL(KT, BB) { \
    gld_lds16(bSt + (size_t)(KT) * KTB,        lds + (BB) + 16384 + widB); \
    gld_lds16(bSt + (size_t)(KT) * KTB + 2048, lds + (BB) + 24576 + widB); \
    gld_lds16(aSt + (size_t)(KT) * KTB,        lds + (BB) + widB); \
    gld_lds16(aSt + (size_t)(KT) * KTB + 2048, lds + (BB) + 8192 + widB); }

__global__ __launch_bounds__(512, 2)
void gemm_dist(const char* __restrict__ Qt, const int* __restrict__ sqi,
               unsigned short* __restrict__ Db) {
    __shared__ char lds[131072];   // 128 KB = 4 bufs x (A0,A1,B0,B1 of 8KB)
    const int tid = threadIdx.x;
    const int wid = tid >> 6, lane = tid & 63;
    const int wr = wid >> 2, wc = wid & 3;
    const int fr = lane & 15, ksub = lane >> 4;
    const int widB = wid * 1024;

    int rA[4], rB[4];
#pragma unroll
    for (int m = 0; m < 4; ++m) rA[m] = (ksub * 128 + m * 16 + fr) * 16;
#pragma unroll
    for (int n = 0; n < 4; ++n) rB[n] = (ksub * 128 + (wc & 1) * 64 + n * 16 + fr) * 16;
    const int aRegOff = wr * 8192;
    const int bRegOff = 16384 + (wc >> 1) * 8192;

    const int swz = (blockIdx.x & 7) * 32 + (blockIdx.x >> 3);  // XCD-chunked
    const int bi = swz >> 4, bj = swz & 15;
    const int rowC0 = bi * 256, colC0 = bj * 256;

    const int srow = tid & 127;
    const int sks = tid >> 7;
    const char* aSt = Qt + ((size_t)sks * 4096 + rowC0 + srow) * 16;
    const char* bSt = Qt + ((size_t)sks * 4096 + colC0 + srow) * 16;

    intx4 acc[2][4][4];
#pragma unroll
    for (int a0 = 0; a0 < 2; ++a0)
#pragma unroll
    for (int a1 = 0; a1 < 4; ++a1)
#pragma unroll
    for (int a2 = 0; a2 < 4; ++a2) acc[a0][a1][a2] = (intx4){0, 0, 0, 0};
    intx4 aflo[4], afhi[4], bfv[4];

    // prologue: stage t0 -> buf0, t1 -> buf1; vmcnt(4) = t0 landed
    STG_ALL(0, 0);
    STG_ALL(1, 32768);
    VMCNT4();
    BAR();

    int cb = 0, sb = 65536;   // current / staging(t+2) buffer byte base
    for (int t = 0; t < NKT; ++t) {
        const char* bufA = lds + cb + aRegOff;
        const char* bufBp = lds + cb + bRegOff;
        // RD all 12 b128 for tile t
#pragma unroll
        for (int m = 0; m < 4; ++m) aflo[m] = *(const intx4*)(bufA + rA[m]);
#pragma unroll
        for (int m = 0; m < 4; ++m) afhi[m] = *(const intx4*)(bufA + 1024 + rA[m]);
#pragma unroll
        for (int n = 0; n < 4; ++n) bfv[n] = *(const intx4*)(bufBp + rB[n]);
        // stage tile t+2 into buf[(t+2)%4]
        if (t < NKT - 2) { STG_ALL(t + 2, sb); VMCNT4(); }
        else if (t == NKT - 2) { VMCNT0(); }
        BAR();
        PRIO1(); MM8(0, aflo); MM8(1, afhi); PRIO0();
        cb += 32768; if (cb >= 131072) cb = 0;
        sb += 32768; if (sb >= 131072) sb = 0;
    }

    // epilogue: D[i][j] = bf16( (v>0) ? sqrt(v)/24 : 1e-6 ), v exact int32
#pragma unroll
    for (int MH = 0; MH < 2; ++MH)
#pragma unroll
    for (int n = 0; n < 4; ++n) {
        const int col = colC0 + wc * 64 + n * 16 + fr;
        const int sqc = sqi[col];
#pragma unroll
        for (int m = 0; m < 4; ++m) {
            const int row0 = rowC0 + wr * 128 + MH * 64 + m * 16 + ksub * 4;
#pragma unroll
            for (int r = 0; r < 4; ++r) {
                const int v = sqi[row0 + r] + sqc - 2 * acc[MH][n][m][r];
                const float d = (v > 0) ? sqrtf((float)v) * QINV : 1e-6f;
                Db[(size_t)(row0 + r) * N_DIM + col] = f2bf(d);
            }
        }
    }
}

// ---- Kernel 2: fused row stats + third-class scan + loss (bf16 D) ----------
__global__ __launch_bounds__(256)
void stats_loss(const unsigned short* __restrict__ Db, const int* __restrict__ tgt,
                float* __restrict__ lossArr) {
    const int i = blockIdx.x, tid = threadIdx.x;
    const int lane = tid & 63, wave = tid >> 6;
    const int ti = tgt[i];
    const unsigned short* row = Db + (size_t)i * N_DIM;
    ull kmax = 0ULL, kmin = ~0ULL;
#pragma unroll
    for (int it = 0; it < 2; ++it) {
        const int j0 = (it * 256 + tid) * 8;
        ushort8 d = *(const ushort8*)(row + j0);
        intx4 ta = *(const intx4*)(tgt + j0);
        intx4 tb = *(const intx4*)(tgt + j0 + 4);
#pragma unroll
        for (int e = 0; e < 8; ++e) {
            const int j = j0 + e;
            const int tl = (e < 4) ? ta[e] : tb[e - 4];
            const ull db = (ull)d[e] << 32;
            if (tl == ti) { ull k = db | (unsigned)j;  if (k > kmax) kmax = k; }
            else          { ull k = db | (unsigned)~j; if (k < kmin) kmin = k; }
        }
    }
#pragma unroll
    for (int off = 32; off; off >>= 1) {
        ull o = __shfl_xor(kmax, off); if (o > kmax) kmax = o;
        o = __shfl_xor(kmin, off);     if (o < kmin) kmin = o;
    }
    __shared__ ull sW[8];
    if (lane == 0) { sW[wave] = kmax; sW[4 + wave] = kmin; }
    __syncthreads();
    ull km = sW[0], kn = sW[4];
#pragma unroll
    for (int w2 = 1; w2 < 4; ++w2) {
        if (sW[w2] > km) km = sW[w2];
        if (sW[4 + w2] < kn) kn = sW[4 + w2];
    }
    const float ap = bf2f((unsigned short)(km >> 32));
    const int p = (int)(unsigned)(km & 0xFFFFFFFFu);
    const float an = bf2f((unsigned short)(kn >> 32));
    const int q = (int)~(unsigned)(kn & 0xFFFFFFFFu);

    // phase 2: third-class min over row q (labels != ti and != tgt[q])
    const int lq = tgt[q];
    const unsigned short* rowq = Db + (size_t)q * N_DIM;
    ull kr = ~0ULL;
#pragma unroll
    for (int it = 0; it < 2; ++it) {
        const int j0 = (it * 256 + tid) * 8;
        ushort8 d = *(const ushort8*)(rowq + j0);
        intx4 ta = *(const intx4*)(tgt + j0);
        intx4 tb = *(const intx4*)(tgt + j0 + 4);
#pragma unroll
        for (int e = 0; e < 8; ++e) {
            const int j = j0 + e;
            const int tl = (e < 4) ? ta[e] : tb[e - 4];
            if (tl != ti && tl != lq) {
                ull k = ((ull)d[e] << 32) | (unsigned)~j;
                if (k < kr) kr = k;
            }
        }
    }
#pragma unroll
    for (int off = 32; off; off >>= 1) {
        ull o = __shfl_xor(kr, off); if (o < kr) kr = o;
    }
    __shared__ ull sR[4];
    if (lane == 0) sR[wave] = kr;
    __syncthreads();
    if (tid == 0) {
        ull kk = sR[0];
#pragma unroll
        for (int w2 = 1; w2 < 4; ++w2) if (sR[w2] < kk) kk = sR[w2];
        const float okmin = bf2f((unsigned short)(kk >> 32));
        const int r = (int)~(unsigned)(kk & 0xFFFFFFFFu);
        const float an2 = bf2f(Db[(size_t)p * N_DIM + q]);
        const float an3 = bf2f(Db[(size_t)i * N_DIM + r]);
        lossArr[i] = fmaxf(ap - an, 0.f) + fabsf(an - an2) + fabsf(an3 - okmin);
    }
}

// ---- Kernel 3: final sum / n ------------------------------------------------
__global__ __launch_bounds__(256)
void finred(const float* __restrict__ lossArr, float* __restrict__ out) {
    const int tid = threadIdx.x;
    float s = 0.f;
    for (int j = tid; j < N_DIM; j += 256) s += lossArr[j];
#pragma unroll
    for (int off = 32; off; off >>= 1) s += __shfl_down(s, off);
    __shared__ float w[4];
    const int wave = tid >> 6, lane = tid & 63;
    if (lane == 0) w[wave] = s;
    __syncthreads();
    if (tid == 0) out[0] = (w[0] + w[1] + w[2] + w[3]) * (1.0f / (float)N_DIM);
}

extern "C" void kernel_launch(void* const* d_in, const int* in_sizes, int n_in,
                              void* d_out, int out_size, void* d_ws, size_t ws_size,
                              hipStream_t stream) {
    const float* X = (const float*)d_in[0];
    const int* tgt = (const int*)d_in[1];
    float* out = (float*)d_out;

    char* w = (char*)d_ws;
    char* Qt = w;                                             // 8 MB (k-major)
    unsigned short* Db = (unsigned short*)(w + ((size_t)16 << 20));  // 32 MB bf16
    int* sqi = (int*)(w + ((size_t)80 << 20));                // 16 KB
    float* lossArr = (float*)(sqi + N_DIM);                   // 16 KB

    prep_kernel<<<N_DIM, 256, 0, stream>>>(X, Qt, sqi);
    gemm_dist<<<256, 512, 0, stream>>>(Qt, sqi, Db);
    stats_loss<<<N_DIM, 256, 0, stream>>>(Db, tgt, lossArr);
    finred<<<1, 256, 0, stream>>>(lossArr, out);
}